// Round 1
// baseline (1773.167 us; speedup 1.0000x reference)
//
#include <hip/hip_runtime.h>

#define B_   8
#define S_   512
#define V_   32000
#define CTX_ 8
#define NC_  512
#define D_   256
#define NH_  4
#define L_   4
#define FF_  512
#define HD_  64
#define BS_  4096   // B_*S_

// ---------------------------------------------------------------------------
// Embedding: scores[b,s,:] = mean_c ram_table[win[b,s,c], :]   (NC_=512 cols)
// win[b,s,c] = (s+c-7 < 0) ? PAD(0) : token_ids[b, s+c-7]
// ---------------------------------------------------------------------------
__global__ __launch_bounds__(256) void embed_scores_kernel(
    const int* __restrict__ tok, const float* __restrict__ table,
    float* __restrict__ scores)
{
    int bs = blockIdx.x;          // 0..4095
    int b = bs >> 9, s = bs & 511;
    int j = threadIdx.x;          // 0..255, handles cols j and j+256
    float a0 = 0.f, a1 = 0.f;
    #pragma unroll
    for (int c = 0; c < CTX_; ++c) {
        int pos = s + c - (CTX_ - 1);
        int t = (pos < 0) ? 0 : tok[b * S_ + pos];
        const float* row = table + (size_t)t * NC_;
        a0 += row[j];
        a1 += row[j + 256];
    }
    scores[(size_t)bs * NC_ + j]       = a0 * 0.125f;
    scores[(size_t)bs * NC_ + j + 256] = a1 * 0.125f;
}

// ---------------------------------------------------------------------------
// LayerNorm over D_=256, one row per block (256 threads)
// ---------------------------------------------------------------------------
__global__ __launch_bounds__(256) void ln_kernel(
    const float* __restrict__ x, const float* __restrict__ sc,
    const float* __restrict__ bi, float* __restrict__ out)
{
    __shared__ float red[256];
    int row = blockIdx.x;
    int t = threadIdx.x;
    float v = x[(size_t)row * D_ + t];
    red[t] = v;
    __syncthreads();
    for (int o = 128; o > 0; o >>= 1) { if (t < o) red[t] += red[t + o]; __syncthreads(); }
    float mean = red[0] * (1.f / D_);
    __syncthreads();
    float d = v - mean;
    red[t] = d * d;
    __syncthreads();
    for (int o = 128; o > 0; o >>= 1) { if (t < o) red[t] += red[t + o]; __syncthreads(); }
    float var = red[0] * (1.f / D_);
    float r = rsqrtf(var + 1e-5f);
    out[(size_t)row * D_ + t] = d * r * sc[t] + bi[t];
}

// ---------------------------------------------------------------------------
// Generic f32 GEMM: C = epilogue((A[MxK] @ B[KxN] + bias) * alpha ...)
// Tile 64x64, BK=64, 256 threads, 4x4 per thread. M,N,K multiples of 64.
// flags: 1 = relu, 2 = qkv head-layout output, 4 = add pos_emb[(row&511)*N+col]
// ---------------------------------------------------------------------------
__global__ __launch_bounds__(256) void gemm_kernel(
    const float* __restrict__ A, const float* __restrict__ B,
    const float* __restrict__ bias, const float* __restrict__ extra,
    const float* __restrict__ resid, const float* __restrict__ pos,
    float* __restrict__ C, int M, int N, int K, float alpha, int flags)
{
    __shared__ float As[64][68];
    __shared__ float Bs[64][68];
    int col0 = blockIdx.x * 64;
    int row0 = blockIdx.y * 64;
    int t = threadIdx.x;
    int tx = t & 15, ty = t >> 4;
    int lc = (t & 15) * 4;   // load col (float4)
    int lr = t >> 4;         // load row base
    float acc[4][4] = {};
    for (int k0 = 0; k0 < K; k0 += 64) {
        #pragma unroll
        for (int p = 0; p < 4; ++p) {
            int r = lr + p * 16;
            *reinterpret_cast<float4*>(&As[r][lc]) =
                *reinterpret_cast<const float4*>(&A[(size_t)(row0 + r) * K + k0 + lc]);
            *reinterpret_cast<float4*>(&Bs[r][lc]) =
                *reinterpret_cast<const float4*>(&B[(size_t)(k0 + r) * N + col0 + lc]);
        }
        __syncthreads();
        #pragma unroll 8
        for (int kk = 0; kk < 64; ++kk) {
            float4 b4 = *reinterpret_cast<const float4*>(&Bs[kk][tx * 4]);
            float a0 = As[ty * 4 + 0][kk];
            float a1 = As[ty * 4 + 1][kk];
            float a2 = As[ty * 4 + 2][kk];
            float a3 = As[ty * 4 + 3][kk];
            acc[0][0] += a0 * b4.x; acc[0][1] += a0 * b4.y; acc[0][2] += a0 * b4.z; acc[0][3] += a0 * b4.w;
            acc[1][0] += a1 * b4.x; acc[1][1] += a1 * b4.y; acc[1][2] += a1 * b4.z; acc[1][3] += a1 * b4.w;
            acc[2][0] += a2 * b4.x; acc[2][1] += a2 * b4.y; acc[2][2] += a2 * b4.z; acc[2][3] += a2 * b4.w;
            acc[3][0] += a3 * b4.x; acc[3][1] += a3 * b4.y; acc[3][2] += a3 * b4.z; acc[3][3] += a3 * b4.w;
        }
        __syncthreads();
    }
    #pragma unroll
    for (int i = 0; i < 4; ++i) {
        int row = row0 + ty * 4 + i;
        #pragma unroll
        for (int j = 0; j < 4; ++j) {
            int col = col0 + tx * 4 + j;
            float v = acc[i][j];
            if (bias) v += bias[col];
            v *= alpha;
            if (flags & 4) v += pos[(size_t)(row & 511) * N + col];
            if (extra) v += extra[col];
            if (resid) v += resid[(size_t)row * N + col];
            if (flags & 1) v = fmaxf(v, 0.f);
            if (flags & 2) {
                int bb = row >> 9, ss = row & 511;
                int hh = col >> 6, dd = col & 63;
                C[((((size_t)bb * NH_ + hh) * S_ + ss) << 6) + dd] = v;
            } else {
                C[(size_t)row * N + col] = v;
            }
        }
    }
}

// ---------------------------------------------------------------------------
// Attention scores: att[bh, q, k] = sum_d Q[bh,q,d]*K[bh,k,d]
// (q already scaled by 1/8). Blocks with ktile>qtile skipped (softmax ignores).
// ---------------------------------------------------------------------------
__global__ __launch_bounds__(256) void att_scores_kernel(
    const float* __restrict__ q, const float* __restrict__ k,
    float* __restrict__ att)
{
    int kt = blockIdx.x, qt = blockIdx.y, bh = blockIdx.z;
    if (kt > qt) return;
    __shared__ float Qs[64][68];
    __shared__ float Ks[64][68];
    const float* Qp = q + ((size_t)bh * S_ + qt * 64) * HD_;
    const float* Kp = k + ((size_t)bh * S_ + kt * 64) * HD_;
    int t = threadIdx.x, tx = t & 15, ty = t >> 4;
    int lc = (t & 15) * 4, lr = t >> 4;
    #pragma unroll
    for (int p = 0; p < 4; ++p) {
        int r = lr + p * 16;
        *reinterpret_cast<float4*>(&Qs[r][lc]) =
            *reinterpret_cast<const float4*>(&Qp[r * HD_ + lc]);
        *reinterpret_cast<float4*>(&Ks[r][lc]) =
            *reinterpret_cast<const float4*>(&Kp[r * HD_ + lc]);
    }
    __syncthreads();
    float acc[4][4] = {};
    #pragma unroll 8
    for (int d = 0; d < 64; ++d) {
        float qv[4], kv[4];
        #pragma unroll
        for (int i = 0; i < 4; ++i) qv[i] = Qs[ty * 4 + i][d];
        #pragma unroll
        for (int j = 0; j < 4; ++j) kv[j] = Ks[tx * 4 + j][d];
        #pragma unroll
        for (int i = 0; i < 4; ++i)
            #pragma unroll
            for (int j = 0; j < 4; ++j)
                acc[i][j] += qv[i] * kv[j];
    }
    #pragma unroll
    for (int i = 0; i < 4; ++i) {
        int qq = qt * 64 + ty * 4 + i;
        #pragma unroll
        for (int j = 0; j < 4; ++j) {
            int kk = kt * 64 + tx * 4 + j;
            att[((size_t)bh * S_ + qq) * S_ + kk] = acc[i][j];
        }
    }
}

// ---------------------------------------------------------------------------
// Row softmax over k<=q (causal); zeros the tail so PV is a dense GEMM.
// One wave per (bh, q) row.
// ---------------------------------------------------------------------------
__global__ __launch_bounds__(64) void softmax_kernel(float* __restrict__ att)
{
    int q = blockIdx.x;
    int bh = blockIdx.y;
    float* row = att + ((size_t)bh * S_ + q) * S_;
    int t = threadIdx.x;
    int n = q + 1;
    float m = -1e30f;
    for (int i = t; i < n; i += 64) m = fmaxf(m, row[i]);
    #pragma unroll
    for (int o = 32; o > 0; o >>= 1) m = fmaxf(m, __shfl_xor(m, o));
    float sum = 0.f;
    for (int i = t; i < n; i += 64) { float e = __expf(row[i] - m); row[i] = e; sum += e; }
    #pragma unroll
    for (int o = 32; o > 0; o >>= 1) sum += __shfl_xor(sum, o);
    float inv = 1.f / sum;
    for (int i = t; i < S_; i += 64) row[i] = (i < n) ? row[i] * inv : 0.f;
}

// ---------------------------------------------------------------------------
// PV: out(B,S,D layout) <- att[bh](512x512) @ V[bh](512x64)
// ---------------------------------------------------------------------------
__global__ __launch_bounds__(256) void att_pv_kernel(
    const float* __restrict__ att, const float* __restrict__ v,
    float* __restrict__ out)
{
    int rt = blockIdx.x;   // q tile 0..7
    int bh = blockIdx.y;   // 0..31
    __shared__ float As[64][68];
    __shared__ float Bs[64][68];
    const float* Ap = att + ((size_t)bh * S_ + rt * 64) * S_;
    const float* Vp = v + (size_t)bh * S_ * HD_;
    int t = threadIdx.x, tx = t & 15, ty = t >> 4;
    int lc = (t & 15) * 4, lr = t >> 4;
    float acc[4][4] = {};
    for (int k0 = 0; k0 < S_; k0 += 64) {
        #pragma unroll
        for (int p = 0; p < 4; ++p) {
            int r = lr + p * 16;
            *reinterpret_cast<float4*>(&As[r][lc]) =
                *reinterpret_cast<const float4*>(&Ap[(size_t)r * S_ + k0 + lc]);
            *reinterpret_cast<float4*>(&Bs[r][lc]) =
                *reinterpret_cast<const float4*>(&Vp[(size_t)(k0 + r) * HD_ + lc]);
        }
        __syncthreads();
        #pragma unroll 8
        for (int kk = 0; kk < 64; ++kk) {
            float4 b4 = *reinterpret_cast<const float4*>(&Bs[kk][tx * 4]);
            float a0 = As[ty * 4 + 0][kk];
            float a1 = As[ty * 4 + 1][kk];
            float a2 = As[ty * 4 + 2][kk];
            float a3 = As[ty * 4 + 3][kk];
            acc[0][0] += a0 * b4.x; acc[0][1] += a0 * b4.y; acc[0][2] += a0 * b4.z; acc[0][3] += a0 * b4.w;
            acc[1][0] += a1 * b4.x; acc[1][1] += a1 * b4.y; acc[1][2] += a1 * b4.z; acc[1][3] += a1 * b4.w;
            acc[2][0] += a2 * b4.x; acc[2][1] += a2 * b4.y; acc[2][2] += a2 * b4.z; acc[2][3] += a2 * b4.w;
            acc[3][0] += a3 * b4.x; acc[3][1] += a3 * b4.y; acc[3][2] += a3 * b4.z; acc[3][3] += a3 * b4.w;
        }
        __syncthreads();
    }
    int bb = bh >> 2, hh = bh & 3;
    #pragma unroll
    for (int i = 0; i < 4; ++i) {
        int ss = rt * 64 + ty * 4 + i;
        #pragma unroll
        for (int j = 0; j < 4; ++j) {
            int dd = tx * 4 + j;
            out[((size_t)bb * S_ + ss) * D_ + hh * HD_ + dd] = acc[i][j];
        }
    }
}

// ---------------------------------------------------------------------------
// CA constant: cc[l,:] = ca_bv[l] @ ca_Wo[l] + ca_bo[l]   (exact CA reduction)
// ---------------------------------------------------------------------------
__global__ __launch_bounds__(256) void cc_kernel(
    const float* __restrict__ bv, const float* __restrict__ Wo,
    const float* __restrict__ bo, float* __restrict__ cc)
{
    int l = blockIdx.x;
    int j = threadIdx.x;
    const float* w = Wo + (size_t)l * D_ * D_;
    const float* b = bv + l * D_;
    float acc = 0.f;
    for (int d = 0; d < D_; ++d) acc += b[d] * w[(size_t)d * D_ + j];
    cc[l * D_ + j] = acc + bo[l * D_ + j];
}

// ---------------------------------------------------------------------------
extern "C" void kernel_launch(void* const* d_in, const int* in_sizes, int n_in,
                              void* d_out, int out_size, void* d_ws, size_t ws_size,
                              hipStream_t stream)
{
    const int*   tok     = (const int*)  d_in[0];
    const float* ram     = (const float*)d_in[1];
    const float* proj_W  = (const float*)d_in[2];
    const float* proj_b  = (const float*)d_in[3];
    const float* pos_emb = (const float*)d_in[4];
    const float* sa_Wq   = (const float*)d_in[5];
    const float* sa_Wk   = (const float*)d_in[6];
    const float* sa_Wv   = (const float*)d_in[7];
    const float* sa_Wo   = (const float*)d_in[8];
    const float* sa_bq   = (const float*)d_in[9];
    const float* sa_bk   = (const float*)d_in[10];
    const float* sa_bv   = (const float*)d_in[11];
    const float* sa_bo   = (const float*)d_in[12];
    const float* ca_Wo   = (const float*)d_in[16];
    const float* ca_bv   = (const float*)d_in[19];
    const float* ca_bo   = (const float*)d_in[20];
    const float* ln1_s   = (const float*)d_in[21];
    const float* ln1_b   = (const float*)d_in[22];
    const float* ln3_s   = (const float*)d_in[25];
    const float* ln3_b   = (const float*)d_in[26];
    const float* ff_W1   = (const float*)d_in[27];
    const float* ff_b1   = (const float*)d_in[28];
    const float* ff_W2   = (const float*)d_in[29];
    const float* ff_b2   = (const float*)d_in[30];
    const float* out_W   = (const float*)d_in[31];
    const float* out_b   = (const float*)d_in[32];

    float* out = (float*)d_out;
    float* ws  = (float*)d_ws;

    // x must survive until the final GEMM (which overwrites d_out) -> keep in ws
    float* x  = ws;                       // BS_*D_ = 1,048,576 floats
    float* cc = ws + (size_t)BS_ * D_;    // L_*D_  = 1024 floats

    // everything else scratches the front of d_out (524 MB), overwritten at end
    float* att  = out;                                  // 32*512*512 = 8,388,608
    float* h    = out + (size_t)8 * 1024 * 1024;        // 1,048,576
    float* qb   = h   + (size_t)BS_ * D_;
    float* kb   = qb  + (size_t)BS_ * D_;
    float* vb   = kb  + (size_t)BS_ * D_;
    float* pv   = vb  + (size_t)BS_ * D_;
    float* tbuf = pv  + (size_t)BS_ * D_;               // 2,097,152 (scores/FF hidden)

    cc_kernel<<<L_, 256, 0, stream>>>(ca_bv, ca_Wo, ca_bo, cc);
    embed_scores_kernel<<<BS_, 256, 0, stream>>>(tok, ram, tbuf);
    // x = scores @ proj_W + proj_b + pos_emb
    gemm_kernel<<<dim3(D_ / 64, BS_ / 64), 256, 0, stream>>>(
        tbuf, proj_W, proj_b, nullptr, nullptr, pos_emb, x, BS_, D_, NC_, 1.f, 4);

    for (int l = 0; l < L_; ++l) {
        const float* Wq = sa_Wq + (size_t)l * D_ * D_;
        const float* Wk = sa_Wk + (size_t)l * D_ * D_;
        const float* Wv = sa_Wv + (size_t)l * D_ * D_;
        const float* Wo = sa_Wo + (size_t)l * D_ * D_;

        ln_kernel<<<BS_, 256, 0, stream>>>(x, ln1_s + l * D_, ln1_b + l * D_, h);
        // q pre-scaled by 1/sqrt(hd)=0.125, head-major layout
        gemm_kernel<<<dim3(D_ / 64, BS_ / 64), 256, 0, stream>>>(
            h, Wq, sa_bq + l * D_, nullptr, nullptr, nullptr, qb, BS_, D_, D_, 0.125f, 2);
        gemm_kernel<<<dim3(D_ / 64, BS_ / 64), 256, 0, stream>>>(
            h, Wk, sa_bk + l * D_, nullptr, nullptr, nullptr, kb, BS_, D_, D_, 1.f, 2);
        gemm_kernel<<<dim3(D_ / 64, BS_ / 64), 256, 0, stream>>>(
            h, Wv, sa_bv + l * D_, nullptr, nullptr, nullptr, vb, BS_, D_, D_, 1.f, 2);

        att_scores_kernel<<<dim3(8, 8, 32), 256, 0, stream>>>(qb, kb, att);
        softmax_kernel<<<dim3(S_, 32), 64, 0, stream>>>(att);
        att_pv_kernel<<<dim3(8, 32), 256, 0, stream>>>(att, vb, pv);

        // x = x + pv @ Wo + bo + cc[l]   (cc folds the exact cross-attn block)
        gemm_kernel<<<dim3(D_ / 64, BS_ / 64), 256, 0, stream>>>(
            pv, Wo, sa_bo + l * D_, cc + l * D_, x, nullptr, x, BS_, D_, D_, 1.f, 0);

        ln_kernel<<<BS_, 256, 0, stream>>>(x, ln3_s + l * D_, ln3_b + l * D_, h);
        gemm_kernel<<<dim3(FF_ / 64, BS_ / 64), 256, 0, stream>>>(
            h, ff_W1 + (size_t)l * D_ * FF_, ff_b1 + l * FF_, nullptr, nullptr, nullptr,
            tbuf, BS_, FF_, D_, 1.f, 1);
        gemm_kernel<<<dim3(D_ / 64, BS_ / 64), 256, 0, stream>>>(
            tbuf, ff_W2 + (size_t)l * FF_ * D_, ff_b2 + l * D_, nullptr, x, nullptr,
            x, BS_, D_, FF_, 1.f, 0);
    }

    // logits = x @ out_W + out_b  (overwrites all of d_out, reads only ws + weights)
    gemm_kernel<<<dim3(V_ / 64, BS_ / 64), 256, 0, stream>>>(
        x, out_W, out_b, nullptr, nullptr, nullptr, out, BS_, V_, D_, 1.f, 0);
}

// Round 2
// 1039.522 us; speedup vs baseline: 1.7058x; 1.7058x over previous
//
#include <hip/hip_runtime.h>

#define B_   8
#define S_   512
#define V_   32000
#define CTX_ 8
#define NC_  512
#define D_   256
#define NH_  4
#define L_   4
#define FF_  512
#define HD_  64
#define BS_  4096   // B_*S_

typedef __attribute__((ext_vector_type(8))) short bf16x8;
typedef __attribute__((ext_vector_type(4))) float f32x4;

__device__ inline void gload16(const void* g, void* lds) {
    __builtin_amdgcn_global_load_lds(
        (const __attribute__((address_space(1))) void*)g,
        (__attribute__((address_space(3))) void*)lds, 16, 0, 0);
}

__device__ inline ushort f2b(float f) {   // f32 -> bf16 RNE
    union { float f; unsigned u; } v; v.f = f;
    unsigned u = v.u;
    unsigned r = u + 0x7fffu + ((u >> 16) & 1u);
    return (ushort)(r >> 16);
}

// ---------------------------------------------------------------------------
// Embedding: scores[b,s,:] = mean_c ram_table[win[b,s,c], :]   (NC_=512 cols)
// ---------------------------------------------------------------------------
__global__ __launch_bounds__(256) void embed_scores_kernel(
    const int* __restrict__ tok, const float* __restrict__ table,
    float* __restrict__ scores)
{
    int bs = blockIdx.x;
    int b = bs >> 9, s = bs & 511;
    int j = threadIdx.x;
    float a0 = 0.f, a1 = 0.f;
    #pragma unroll
    for (int c = 0; c < CTX_; ++c) {
        int pos = s + c - (CTX_ - 1);
        int t = (pos < 0) ? 0 : tok[b * S_ + pos];
        const float* row = table + (size_t)t * NC_;
        a0 += row[j];
        a1 += row[j + 256];
    }
    scores[(size_t)bs * NC_ + j]       = a0 * 0.125f;
    scores[(size_t)bs * NC_ + j + 256] = a1 * 0.125f;
}

// ---------------------------------------------------------------------------
// LayerNorm over D_=256, one row per block (256 threads)
// ---------------------------------------------------------------------------
__global__ __launch_bounds__(256) void ln_kernel(
    const float* __restrict__ x, const float* __restrict__ sc,
    const float* __restrict__ bi, float* __restrict__ out)
{
    __shared__ float red[256];
    int row = blockIdx.x;
    int t = threadIdx.x;
    float v = x[(size_t)row * D_ + t];
    red[t] = v;
    __syncthreads();
    for (int o = 128; o > 0; o >>= 1) { if (t < o) red[t] += red[t + o]; __syncthreads(); }
    float mean = red[0] * (1.f / D_);
    __syncthreads();
    float d = v - mean;
    red[t] = d * d;
    __syncthreads();
    for (int o = 128; o > 0; o >>= 1) { if (t < o) red[t] += red[t + o]; __syncthreads(); }
    float var = red[0] * (1.f / D_);
    float r = rsqrtf(var + 1e-5f);
    out[(size_t)row * D_ + t] = d * r * sc[t] + bi[t];
}

// ---------------------------------------------------------------------------
// Generic f32 GEMM (used for all per-layer math + fallback final GEMM)
// flags: 1 = relu, 2 = qkv head-layout output, 4 = add pos_emb
// ---------------------------------------------------------------------------
__global__ __launch_bounds__(256) void gemm_kernel(
    const float* __restrict__ A, const float* __restrict__ B,
    const float* __restrict__ bias, const float* __restrict__ extra,
    const float* __restrict__ resid, const float* __restrict__ pos,
    float* __restrict__ C, int M, int N, int K, float alpha, int flags)
{
    __shared__ float As[64][68];
    __shared__ float Bs[64][68];
    int col0 = blockIdx.x * 64;
    int row0 = blockIdx.y * 64;
    int t = threadIdx.x;
    int tx = t & 15, ty = t >> 4;
    int lc = (t & 15) * 4;
    int lr = t >> 4;
    float acc[4][4] = {};
    for (int k0 = 0; k0 < K; k0 += 64) {
        #pragma unroll
        for (int p = 0; p < 4; ++p) {
            int r = lr + p * 16;
            *reinterpret_cast<float4*>(&As[r][lc]) =
                *reinterpret_cast<const float4*>(&A[(size_t)(row0 + r) * K + k0 + lc]);
            *reinterpret_cast<float4*>(&Bs[r][lc]) =
                *reinterpret_cast<const float4*>(&B[(size_t)(k0 + r) * N + col0 + lc]);
        }
        __syncthreads();
        #pragma unroll 8
        for (int kk = 0; kk < 64; ++kk) {
            float4 b4 = *reinterpret_cast<const float4*>(&Bs[kk][tx * 4]);
            float a0 = As[ty * 4 + 0][kk];
            float a1 = As[ty * 4 + 1][kk];
            float a2 = As[ty * 4 + 2][kk];
            float a3 = As[ty * 4 + 3][kk];
            acc[0][0] += a0 * b4.x; acc[0][1] += a0 * b4.y; acc[0][2] += a0 * b4.z; acc[0][3] += a0 * b4.w;
            acc[1][0] += a1 * b4.x; acc[1][1] += a1 * b4.y; acc[1][2] += a1 * b4.z; acc[1][3] += a1 * b4.w;
            acc[2][0] += a2 * b4.x; acc[2][1] += a2 * b4.y; acc[2][2] += a2 * b4.z; acc[2][3] += a2 * b4.w;
            acc[3][0] += a3 * b4.x; acc[3][1] += a3 * b4.y; acc[3][2] += a3 * b4.z; acc[3][3] += a3 * b4.w;
        }
        __syncthreads();
    }
    #pragma unroll
    for (int i = 0; i < 4; ++i) {
        int row = row0 + ty * 4 + i;
        #pragma unroll
        for (int j = 0; j < 4; ++j) {
            int col = col0 + tx * 4 + j;
            float v = acc[i][j];
            if (bias) v += bias[col];
            v *= alpha;
            if (flags & 4) v += pos[(size_t)(row & 511) * N + col];
            if (extra) v += extra[col];
            if (resid) v += resid[(size_t)row * N + col];
            if (flags & 1) v = fmaxf(v, 0.f);
            if (flags & 2) {
                int bb = row >> 9, ss = row & 511;
                int hh = col >> 6, dd = col & 63;
                C[((((size_t)bb * NH_ + hh) * S_ + ss) << 6) + dd] = v;
            } else {
                C[(size_t)row * N + col] = v;
            }
        }
    }
}

// ---------------------------------------------------------------------------
// Attention scores (causal tiles only)
// ---------------------------------------------------------------------------
__global__ __launch_bounds__(256) void att_scores_kernel(
    const float* __restrict__ q, const float* __restrict__ k,
    float* __restrict__ att)
{
    int kt = blockIdx.x, qt = blockIdx.y, bh = blockIdx.z;
    if (kt > qt) return;
    __shared__ float Qs[64][68];
    __shared__ float Ks[64][68];
    const float* Qp = q + ((size_t)bh * S_ + qt * 64) * HD_;
    const float* Kp = k + ((size_t)bh * S_ + kt * 64) * HD_;
    int t = threadIdx.x, tx = t & 15, ty = t >> 4;
    int lc = (t & 15) * 4, lr = t >> 4;
    #pragma unroll
    for (int p = 0; p < 4; ++p) {
        int r = lr + p * 16;
        *reinterpret_cast<float4*>(&Qs[r][lc]) =
            *reinterpret_cast<const float4*>(&Qp[r * HD_ + lc]);
        *reinterpret_cast<float4*>(&Ks[r][lc]) =
            *reinterpret_cast<const float4*>(&Kp[r * HD_ + lc]);
    }
    __syncthreads();
    float acc[4][4] = {};
    #pragma unroll 8
    for (int d = 0; d < 64; ++d) {
        float qv[4], kv[4];
        #pragma unroll
        for (int i = 0; i < 4; ++i) qv[i] = Qs[ty * 4 + i][d];
        #pragma unroll
        for (int j = 0; j < 4; ++j) kv[j] = Ks[tx * 4 + j][d];
        #pragma unroll
        for (int i = 0; i < 4; ++i)
            #pragma unroll
            for (int j = 0; j < 4; ++j)
                acc[i][j] += qv[i] * kv[j];
    }
    #pragma unroll
    for (int i = 0; i < 4; ++i) {
        int qq = qt * 64 + ty * 4 + i;
        #pragma unroll
        for (int j = 0; j < 4; ++j) {
            int kk = kt * 64 + tx * 4 + j;
            att[((size_t)bh * S_ + qq) * S_ + kk] = acc[i][j];
        }
    }
}

// ---------------------------------------------------------------------------
// Row softmax over k<=q; zeros tail
// ---------------------------------------------------------------------------
__global__ __launch_bounds__(64) void softmax_kernel(float* __restrict__ att)
{
    int q = blockIdx.x;
    int bh = blockIdx.y;
    float* row = att + ((size_t)bh * S_ + q) * S_;
    int t = threadIdx.x;
    int n = q + 1;
    float m = -1e30f;
    for (int i = t; i < n; i += 64) m = fmaxf(m, row[i]);
    #pragma unroll
    for (int o = 32; o > 0; o >>= 1) m = fmaxf(m, __shfl_xor(m, o));
    float sum = 0.f;
    for (int i = t; i < n; i += 64) { float e = __expf(row[i] - m); row[i] = e; sum += e; }
    #pragma unroll
    for (int o = 32; o > 0; o >>= 1) sum += __shfl_xor(sum, o);
    float inv = 1.f / sum;
    for (int i = t; i < S_; i += 64) row[i] = (i < n) ? row[i] * inv : 0.f;
}

// ---------------------------------------------------------------------------
// PV: out(B,S,D) <- att[bh] @ V[bh]
// ---------------------------------------------------------------------------
__global__ __launch_bounds__(256) void att_pv_kernel(
    const float* __restrict__ att, const float* __restrict__ v,
    float* __restrict__ out)
{
    int rt = blockIdx.x;
    int bh = blockIdx.y;
    __shared__ float As[64][68];
    __shared__ float Bs[64][68];
    const float* Ap = att + ((size_t)bh * S_ + rt * 64) * S_;
    const float* Vp = v + (size_t)bh * S_ * HD_;
    int t = threadIdx.x, tx = t & 15, ty = t >> 4;
    int lc = (t & 15) * 4, lr = t >> 4;
    float acc[4][4] = {};
    for (int k0 = 0; k0 < S_; k0 += 64) {
        #pragma unroll
        for (int p = 0; p < 4; ++p) {
            int r = lr + p * 16;
            *reinterpret_cast<float4*>(&As[r][lc]) =
                *reinterpret_cast<const float4*>(&Ap[(size_t)r * S_ + k0 + lc]);
            *reinterpret_cast<float4*>(&Bs[r][lc]) =
                *reinterpret_cast<const float4*>(&Vp[(size_t)(k0 + r) * HD_ + lc]);
        }
        __syncthreads();
        #pragma unroll 8
        for (int kk = 0; kk < 64; ++kk) {
            float4 b4 = *reinterpret_cast<const float4*>(&Bs[kk][tx * 4]);
            float a0 = As[ty * 4 + 0][kk];
            float a1 = As[ty * 4 + 1][kk];
            float a2 = As[ty * 4 + 2][kk];
            float a3 = As[ty * 4 + 3][kk];
            acc[0][0] += a0 * b4.x; acc[0][1] += a0 * b4.y; acc[0][2] += a0 * b4.z; acc[0][3] += a0 * b4.w;
            acc[1][0] += a1 * b4.x; acc[1][1] += a1 * b4.y; acc[1][2] += a1 * b4.z; acc[1][3] += a1 * b4.w;
            acc[2][0] += a2 * b4.x; acc[2][1] += a2 * b4.y; acc[2][2] += a2 * b4.z; acc[2][3] += a2 * b4.w;
            acc[3][0] += a3 * b4.x; acc[3][1] += a3 * b4.y; acc[3][2] += a3 * b4.z; acc[3][3] += a3 * b4.w;
        }
        __syncthreads();
    }
    int bb = bh >> 2, hh = bh & 3;
    #pragma unroll
    for (int i = 0; i < 4; ++i) {
        int ss = rt * 64 + ty * 4 + i;
        #pragma unroll
        for (int j = 0; j < 4; ++j) {
            int dd = tx * 4 + j;
            out[((size_t)bb * S_ + ss) * D_ + hh * HD_ + dd] = acc[i][j];
        }
    }
}

// ---------------------------------------------------------------------------
// CA constant: cc[l,:] = ca_bv[l] @ ca_Wo[l] + ca_bo[l]
// ---------------------------------------------------------------------------
__global__ __launch_bounds__(256) void cc_kernel(
    const float* __restrict__ bv, const float* __restrict__ Wo,
    const float* __restrict__ bo, float* __restrict__ cc)
{
    int l = blockIdx.x;
    int j = threadIdx.x;
    const float* w = Wo + (size_t)l * D_ * D_;
    const float* b = bv + l * D_;
    float acc = 0.f;
    for (int d = 0; d < D_; ++d) acc += b[d] * w[(size_t)d * D_ + j];
    cc[l * D_ + j] = acc + bo[l * D_ + j];
}

// ---------------------------------------------------------------------------
// f32 -> bf16 elementwise (float4 / ushort4)
// ---------------------------------------------------------------------------
__global__ __launch_bounds__(256) void f32_to_bf16_kernel(
    const float* __restrict__ in, ushort* __restrict__ out, int n4)
{
    int i = blockIdx.x * 256 + threadIdx.x;
    if (i >= n4) return;
    float4 v = reinterpret_cast<const float4*>(in)[i];
    ushort4 o;
    o.x = f2b(v.x); o.y = f2b(v.y); o.z = f2b(v.z); o.w = f2b(v.w);
    reinterpret_cast<ushort4*>(out)[i] = o;
}

// ---------------------------------------------------------------------------
// out_W f32 [256][32000] -> bf16 [32000][256] (tiled transpose)
// grid (1000, 8), block (32, 8)
// ---------------------------------------------------------------------------
__global__ void transpose_w_kernel(const float* __restrict__ W,
                                   ushort* __restrict__ Wb)
{
    __shared__ float tile[32][33];
    int n0 = blockIdx.x * 32, k0 = blockIdx.y * 32;
    for (int i = threadIdx.y; i < 32; i += 8)
        tile[i][threadIdx.x] = W[(size_t)(k0 + i) * V_ + n0 + threadIdx.x];
    __syncthreads();
    for (int i = threadIdx.y; i < 32; i += 8)
        Wb[(size_t)(n0 + i) * D_ + k0 + threadIdx.x] = f2b(tile[threadIdx.x][i]);
}

// ---------------------------------------------------------------------------
// Final logits GEMM, bf16 MFMA: C[4096][32000] = A[4096][256] @ Bt^T + bias
// A bf16 row-major [M][K]; Bt bf16 N-major [N][K]. 128x128 tile, BK=64,
// 4 waves (2x2 of 64x64), mfma_f32_16x16x32_bf16, global_load_lds staging.
// ---------------------------------------------------------------------------
__global__ __launch_bounds__(256) void logits_mfma_kernel(
    const ushort* __restrict__ A, const ushort* __restrict__ Bt,
    const float* __restrict__ bias, float* __restrict__ C)
{
    __shared__ ushort As[128 * 64];
    __shared__ ushort Bs[128 * 64];
    int bid = blockIdx.x;
    // XCD-bijective swizzle: nwg = 8000, 8000/8 = 1000
    int swz = (bid & 7) * 1000 + (bid >> 3);
    int mt = swz & 31;        // m fastest: 32 consecutive blocks share a B panel
    int nt = swz >> 5;
    int row0 = mt << 7, col0 = nt << 7;
    int t = threadIdx.x;
    int w = t >> 6, lane = t & 63;
    int wr = w >> 1, wc = w & 1;

    f32x4 acc[4][4] = {};
    int srow = lane >> 3;          // 0..7 row within 8-row chunk
    int scol = (lane & 7) * 8;     // bf16 col (16B per lane)

    for (int ks = 0; ks < 4; ++ks) {
        int k0 = ks * 64;
        #pragma unroll
        for (int c = 0; c < 4; ++c) {
            int chunk = w * 4 + c;               // 0..15 (1KB each)
            int r = chunk * 8 + srow;            // tile row 0..127
            gload16(A  + (size_t)(row0 + r) * 256 + k0 + scol, As + chunk * 512);
            gload16(Bt + (size_t)(col0 + r) * 256 + k0 + scol, Bs + chunk * 512);
        }
        __syncthreads();
        const ushort* Ab = As + ((wr * 64 + (lane & 15)) * 64) + (lane >> 4) * 8;
        const ushort* Bb = Bs + ((wc * 64 + (lane & 15)) * 64) + (lane >> 4) * 8;
        #pragma unroll
        for (int kk = 0; kk < 2; ++kk) {
            bf16x8 a[4], b[4];
            #pragma unroll
            for (int m = 0; m < 4; ++m)
                a[m] = *reinterpret_cast<const bf16x8*>(Ab + m * 16 * 64 + kk * 32);
            #pragma unroll
            for (int n = 0; n < 4; ++n)
                b[n] = *reinterpret_cast<const bf16x8*>(Bb + n * 16 * 64 + kk * 32);
            #pragma unroll
            for (int m = 0; m < 4; ++m)
                #pragma unroll
                for (int n = 0; n < 4; ++n)
                    acc[m][n] = __builtin_amdgcn_mfma_f32_16x16x32_bf16(
                        a[m], b[n], acc[m][n], 0, 0, 0);
        }
        __syncthreads();
    }

    int lr = (lane >> 4) * 4;
    int lc = lane & 15;
    #pragma unroll
    for (int n = 0; n < 4; ++n) {
        int col = col0 + wc * 64 + n * 16 + lc;
        float bn = bias[col];
        #pragma unroll
        for (int m = 0; m < 4; ++m) {
            int row = row0 + wr * 64 + m * 16 + lr;
            #pragma unroll
            for (int r = 0; r < 4; ++r) {
                __builtin_nontemporal_store(acc[m][n][r] + bn,
                                            &C[(size_t)(row + r) * V_ + col]);
            }
        }
    }
}

// ---------------------------------------------------------------------------
extern "C" void kernel_launch(void* const* d_in, const int* in_sizes, int n_in,
                              void* d_out, int out_size, void* d_ws, size_t ws_size,
                              hipStream_t stream)
{
    const int*   tok     = (const int*)  d_in[0];
    const float* ram     = (const float*)d_in[1];
    const float* proj_W  = (const float*)d_in[2];
    const float* proj_b  = (const float*)d_in[3];
    const float* pos_emb = (const float*)d_in[4];
    const float* sa_Wq   = (const float*)d_in[5];
    const float* sa_Wk   = (const float*)d_in[6];
    const float* sa_Wv   = (const float*)d_in[7];
    const float* sa_Wo   = (const float*)d_in[8];
    const float* sa_bq   = (const float*)d_in[9];
    const float* sa_bk   = (const float*)d_in[10];
    const float* sa_bv   = (const float*)d_in[11];
    const float* sa_bo   = (const float*)d_in[12];
    const float* ca_Wo   = (const float*)d_in[16];
    const float* ca_bv   = (const float*)d_in[19];
    const float* ca_bo   = (const float*)d_in[20];
    const float* ln1_s   = (const float*)d_in[21];
    const float* ln1_b   = (const float*)d_in[22];
    const float* ln3_s   = (const float*)d_in[25];
    const float* ln3_b   = (const float*)d_in[26];
    const float* ff_W1   = (const float*)d_in[27];
    const float* ff_b1   = (const float*)d_in[28];
    const float* ff_W2   = (const float*)d_in[29];
    const float* ff_b2   = (const float*)d_in[30];
    const float* out_W   = (const float*)d_in[31];
    const float* out_b   = (const float*)d_in[32];

    float* out = (float*)d_out;
    float* ws  = (float*)d_ws;

    // ws layout: x | cc | xb(bf16) | Wb(bf16)
    float*  x  = ws;                              // BS_*D_ floats
    float*  cc = ws + (size_t)BS_ * D_;           // L_*D_ floats
    ushort* xb = (ushort*)(cc + L_ * D_);         // BS_*D_ bf16
    ushort* Wb = xb + (size_t)BS_ * D_;           // V_*D_ bf16
    size_t need = ((size_t)BS_ * D_ + L_ * D_) * 4 +
                  (size_t)BS_ * D_ * 2 + (size_t)V_ * D_ * 2;
    bool fast_logits = (ws_size >= need);

    // scratch in the front of d_out (final GEMM overwrites all of it)
    float* att  = out;                                  // 8,388,608
    float* h    = out + (size_t)8 * 1024 * 1024;        // 1,048,576
    float* qb   = h   + (size_t)BS_ * D_;
    float* kb   = qb  + (size_t)BS_ * D_;
    float* vb   = kb  + (size_t)BS_ * D_;
    float* pv   = vb  + (size_t)BS_ * D_;
    float* tbuf = pv  + (size_t)BS_ * D_;               // 2,097,152

    cc_kernel<<<L_, 256, 0, stream>>>(ca_bv, ca_Wo, ca_bo, cc);
    embed_scores_kernel<<<BS_, 256, 0, stream>>>(tok, ram, tbuf);
    gemm_kernel<<<dim3(D_ / 64, BS_ / 64), 256, 0, stream>>>(
        tbuf, proj_W, proj_b, nullptr, nullptr, pos_emb, x, BS_, D_, NC_, 1.f, 4);

    for (int l = 0; l < L_; ++l) {
        const float* Wq = sa_Wq + (size_t)l * D_ * D_;
        const float* Wk = sa_Wk + (size_t)l * D_ * D_;
        const float* Wv = sa_Wv + (size_t)l * D_ * D_;
        const float* Wo = sa_Wo + (size_t)l * D_ * D_;

        ln_kernel<<<BS_, 256, 0, stream>>>(x, ln1_s + l * D_, ln1_b + l * D_, h);
        gemm_kernel<<<dim3(D_ / 64, BS_ / 64), 256, 0, stream>>>(
            h, Wq, sa_bq + l * D_, nullptr, nullptr, nullptr, qb, BS_, D_, D_, 0.125f, 2);
        gemm_kernel<<<dim3(D_ / 64, BS_ / 64), 256, 0, stream>>>(
            h, Wk, sa_bk + l * D_, nullptr, nullptr, nullptr, kb, BS_, D_, D_, 1.f, 2);
        gemm_kernel<<<dim3(D_ / 64, BS_ / 64), 256, 0, stream>>>(
            h, Wv, sa_bv + l * D_, nullptr, nullptr, nullptr, vb, BS_, D_, D_, 1.f, 2);

        att_scores_kernel<<<dim3(8, 8, 32), 256, 0, stream>>>(qb, kb, att);
        softmax_kernel<<<dim3(S_, 32), 64, 0, stream>>>(att);
        att_pv_kernel<<<dim3(8, 32), 256, 0, stream>>>(att, vb, pv);

        gemm_kernel<<<dim3(D_ / 64, BS_ / 64), 256, 0, stream>>>(
            pv, Wo, sa_bo + l * D_, cc + l * D_, x, nullptr, x, BS_, D_, D_, 1.f, 0);

        ln_kernel<<<BS_, 256, 0, stream>>>(x, ln3_s + l * D_, ln3_b + l * D_, h);
        gemm_kernel<<<dim3(FF_ / 64, BS_ / 64), 256, 0, stream>>>(
            h, ff_W1 + (size_t)l * D_ * FF_, ff_b1 + l * FF_, nullptr, nullptr, nullptr,
            tbuf, BS_, FF_, D_, 1.f, 1);
        gemm_kernel<<<dim3(D_ / 64, BS_ / 64), 256, 0, stream>>>(
            tbuf, ff_W2 + (size_t)l * FF_ * D_, ff_b2 + l * D_, nullptr, x, nullptr,
            x, BS_, D_, FF_, 1.f, 0);
    }

    if (fast_logits) {
        f32_to_bf16_kernel<<<(BS_ * D_ / 4 + 255) / 256, 256, 0, stream>>>(
            x, xb, BS_ * D_ / 4);
        transpose_w_kernel<<<dim3(V_ / 32, D_ / 32), dim3(32, 8), 0, stream>>>(out_W, Wb);
        logits_mfma_kernel<<<(V_ / 128) * (BS_ / 128), 256, 0, stream>>>(xb, Wb, out_b, out);
    } else {
        gemm_kernel<<<dim3(V_ / 64, BS_ / 64), 256, 0, stream>>>(
            x, out_W, out_b, nullptr, nullptr, nullptr, out, BS_, V_, D_, 1.f, 0);
    }
}